// Round 4
// baseline (3416.992 us; speedup 1.0000x reference)
//
#include <hip/hip_runtime.h>
#include <hip/hip_bf16.h>
#include <cstddef>

typedef unsigned short u16;
typedef short bf16x8 __attribute__((ext_vector_type(8)));   // 8 bf16 bit-patterns (4 VGPRs)
typedef float f32x4 __attribute__((ext_vector_type(4)));
typedef unsigned short u16x8 __attribute__((ext_vector_type(8)));
typedef unsigned short u16x4 __attribute__((ext_vector_type(4)));

#define MDIM 16384
#define NDIM 512
#define HPAD 520   // 512 + 8 elems: row stride 1040 B (16B-aligned), breaks b128 bank alignment

__device__ __forceinline__ float b2f(u16 u) {
    return __uint_as_float(((unsigned int)u) << 16);
}
__device__ __forceinline__ u16 f2b(float f) {  // round-to-nearest-even
    unsigned int x = __float_as_uint(f);
    x += 0x7fffu + ((x >> 16) & 1u);
    return (u16)(x >> 16);
}
__device__ __forceinline__ float fast_tanh(float x) {
    // tanh(x) = 1 - 2/(e^{2x}+1); exp overflow -> +1, underflow -> -1 (correct limits)
    float e = __expf(2.0f * x);
    return 1.0f - 2.0f * __builtin_amdgcn_rcpf(e + 1.0f);
}

// ---------------------------------------------------------------------------
// Legacy tiled GEMM (input projection only).
// C(rows x 512) = A(rows x KDIM) * Bt(512 x KDIM)^T + bias(fp32)
// EPI 3: +addf (fp32), write Cf fp32 only        (projection -> state)
template <int KDIM, int EPI, bool AF32>
__global__ __launch_bounds__(256, 2) void gemm_bt(
    const void* __restrict__ Avoid, const u16* __restrict__ Bt,
    const float* __restrict__ bias, const float* __restrict__ addf,
    u16* __restrict__ Cb, float* __restrict__ Cf) {
    __shared__ u16 As[128 * 72];
    __shared__ u16 Bs[128 * 72];
    const int tid = threadIdx.x;
    const int m0 = blockIdx.y * 128;
    const int n0 = blockIdx.x * 128;
    const int lane = tid & 63;
    const int wave = tid >> 6;
    const int wm = (wave & 1) * 64;
    const int wn = (wave >> 1) * 64;
    const int lr = lane & 15;
    const int lk = (lane >> 4) * 8;

    f32x4 acc[4][4];
    f32x4 zero = {0.0f, 0.0f, 0.0f, 0.0f};
#pragma unroll
    for (int i = 0; i < 4; ++i)
#pragma unroll
        for (int j = 0; j < 4; ++j) acc[i][j] = zero;

    const int r0 = tid >> 3;
    const int c0 = (tid & 7) * 8;

    for (int kt = 0; kt < KDIM / 64; ++kt) {
        const int k0 = kt * 64;
#pragma unroll
        for (int it = 0; it < 4; ++it) {
            int r = it * 32 + r0;
            if constexpr (AF32) {
                const float* Af = (const float*)Avoid;
                const float* src = Af + (size_t)(m0 + r) * KDIM + k0 + c0;
                f32x4 lo = *(const f32x4*)(src);
                f32x4 hi = *(const f32x4*)(src + 4);
                u16x8 t;
#pragma unroll
                for (int q = 0; q < 4; ++q) { t[q] = f2b(lo[q]); t[q + 4] = f2b(hi[q]); }
                *(u16x8*)(&As[r * 72 + c0]) = t;
            } else {
                const u16* Ab = (const u16*)Avoid;
                *(f32x4*)(&As[r * 72 + c0]) =
                    *(const f32x4*)(Ab + (size_t)(m0 + r) * KDIM + k0 + c0);
            }
            *(f32x4*)(&Bs[r * 72 + c0]) =
                *(const f32x4*)(Bt + (size_t)(n0 + r) * KDIM + k0 + c0);
        }
        __syncthreads();
#pragma unroll
        for (int kk = 0; kk < 2; ++kk) {
            bf16x8 af[4], bw[4];
#pragma unroll
            for (int i = 0; i < 4; ++i) {
                af[i] = __builtin_bit_cast(
                    bf16x8, *(const f32x4*)(&As[(wm + i * 16 + lr) * 72 + kk * 32 + lk]));
                bw[i] = __builtin_bit_cast(
                    bf16x8, *(const f32x4*)(&Bs[(wn + i * 16 + lr) * 72 + kk * 32 + lk]));
            }
#pragma unroll
            for (int i = 0; i < 4; ++i)
#pragma unroll
                for (int j = 0; j < 4; ++j)
                    acc[i][j] = __builtin_amdgcn_mfma_f32_16x16x32_bf16(
                        af[i], bw[j], acc[i][j], 0, 0, 0);
        }
        __syncthreads();
    }
#pragma unroll
    for (int j = 0; j < 4; ++j) {
        const int col = n0 + wn + j * 16 + lr;
        const float bv = bias[col];
#pragma unroll
        for (int i = 0; i < 4; ++i) {
            const int rowb = m0 + wm + i * 16 + (lane >> 4) * 4;
#pragma unroll
            for (int r = 0; r < 4; ++r) {
                float v = acc[i][j][r] + bv;
                size_t off = (size_t)(rowb + r) * NDIM + col;
                if constexpr (EPI == 2) Cb[off] = f2b(v);
                if constexpr (EPI == 3) {
                    v += addf[off];
                    Cf[off] = v;
                }
            }
        }
    }
}

// coalesced fragment-packed K load: g[i][j] = G[kbase + (i*4+j)*2048]
__device__ __forceinline__ void k_load(const u16* __restrict__ G, size_t kbase,
                                       u16x4 (&g)[4][4]) {
#pragma unroll
    for (int i = 0; i < 4; ++i)
#pragma unroll
        for (int j = 0; j < 4; ++j)
            g[i][j] = *(const u16x4*)(G + kbase + (size_t)(i * 4 + j) * 2048);
}

// ---------------------------------------------------------------------------
// Mega-fused dopri5, fragment-resident edition.
// Block = 64 rows, 512 threads (8 waves, each owns a 64-col strip of N=512).
// Everything per-thread lives in the MFMA C/D fragment layout:
//   element (i,j,r) <-> row = i*16 + (lane>>4)*4 + r, col = wn + j*16 + (lane&15)
// - S: f32x4 S[4][4] registers for the whole solve.
// - Two newest k's: bf16 registers kA/kB[4][4] (static parity rotation) ->
//   the newest-K global RAW round-trip is GONE.
// - Only k1..k4 ever hit global, fragment-packed [g=i*4+j][tid] as u16x4 so
//   every load/store is a contiguous b64 stream (512 B/wave). All global K
//   write->read gaps are >= 2 evals (barrier-drained).
// - Staging s = S + sum a*k is pure register VALU -> LDS scatter (the same
//   proven epilogue pattern), then 3 MFMA layers stream weights from L2.
__global__ __launch_bounds__(512, 2) void ode_mega(
    const float* __restrict__ S32,
    const u16* __restrict__ W1t, const float* __restrict__ bb1,
    const u16* __restrict__ W2t, const float* __restrict__ bb2,
    const u16* __restrict__ W3t, const float* __restrict__ bb3,
    u16* __restrict__ G1, u16* __restrict__ G2,
    u16* __restrict__ G3, u16* __restrict__ G4,
    float* __restrict__ OUT) {
    __shared__ u16 As[64 * HPAD];
    __shared__ u16 Hs[64 * HPAD];
    const int tid = threadIdx.x;
    const int lane = tid & 63;
    const int wn = (tid >> 6) * 64;   // wave's 64-col strip
    const int lr = lane & 15;
    const int lq = lane >> 4;         // 0..3
    const int lk = lq * 8;
    const size_t row0 = (size_t)blockIdx.x * 64;
    const size_t kbase = (size_t)blockIdx.x * (16 * 512 * 4) + (size_t)tid * 4;

    constexpr double h = 0.1 / 8.0;
    constexpr float A21 = (float)(h * 1.0 / 5.0);
    constexpr float A31 = (float)(h * 3.0 / 40.0), A32 = (float)(h * 9.0 / 40.0);
    constexpr float A41 = (float)(h * 44.0 / 45.0), A42 = (float)(h * -56.0 / 15.0);
    constexpr float A43 = (float)(h * 32.0 / 9.0);
    constexpr float A51 = (float)(h * 19372.0 / 6561.0), A52 = (float)(h * -25360.0 / 2187.0);
    constexpr float A53 = (float)(h * 64448.0 / 6561.0), A54 = (float)(h * -212.0 / 729.0);
    constexpr float A61 = (float)(h * 9017.0 / 3168.0), A62 = (float)(h * -355.0 / 33.0);
    constexpr float A63 = (float)(h * 46732.0 / 5247.0), A64 = (float)(h * 49.0 / 176.0);
    constexpr float A65 = (float)(h * -5103.0 / 18656.0);
    constexpr float B1c = (float)(h * 35.0 / 384.0), B3c = (float)(h * 500.0 / 1113.0);
    constexpr float B4c = (float)(h * 125.0 / 192.0), B5c = (float)(h * -2187.0 / 6784.0);
    constexpr float B6c = (float)(h * 11.0 / 84.0);

    const f32x4 zf = {0.f, 0.f, 0.f, 0.f};
    f32x4 S[4][4];
#pragma unroll
    for (int i = 0; i < 4; ++i)
#pragma unroll
        for (int j = 0; j < 4; ++j) {
#pragma unroll
            for (int r = 0; r < 4; ++r)
                S[i][j][r] = S32[(row0 + i * 16 + lq * 4 + r) * 512 + wn + j * 16 + lr];
        }

    u16x4 kA[4][4], kB[4][4];
    f32x4 acc[4][4];

#define STAGE_STORE(sv, i, j)                                                      \
    do {                                                                           \
        const int col_ = wn + (j) * 16 + lr;                                       \
        const int rw_ = (i) * 16 + lq * 4;                                         \
        As[(rw_ + 0) * HPAD + col_] = f2b(sv[0]);                                  \
        As[(rw_ + 1) * HPAD + col_] = f2b(sv[1]);                                  \
        As[(rw_ + 2) * HPAD + col_] = f2b(sv[2]);                                  \
        As[(rw_ + 3) * HPAD + col_] = f2b(sv[3]);                                  \
    } while (0)

#define STG_BEGIN                                                                  \
    _Pragma("unroll") for (int i = 0; i < 4; ++i)                                  \
    _Pragma("unroll") for (int j = 0; j < 4; ++j) {                                \
        f32x4 sv = S[i][j];

#define ADDT(c, K)                                                                 \
        {                                                                          \
            u16x4 t_ = (K)[i][j];                                                  \
            _Pragma("unroll") for (int r_ = 0; r_ < 4; ++r_)                       \
                sv[r_] += (c) * b2f(t_[r_]);                                       \
        }

#define STG_END                                                                    \
        STAGE_STORE(sv, i, j);                                                     \
    }

#define LAYER(SRC, WT)                                                             \
    do {                                                                           \
        _Pragma("unroll") for (int i_ = 0; i_ < 4; ++i_)                           \
            _Pragma("unroll") for (int j_ = 0; j_ < 4; ++j_) acc[i_][j_] = zf;     \
        _Pragma("unroll 2") for (int kt = 0; kt < 16; ++kt) {                      \
            bf16x8 af[4], bw[4];                                                   \
            _Pragma("unroll") for (int j_ = 0; j_ < 4; ++j_)                       \
                bw[j_] = __builtin_bit_cast(bf16x8,                                \
                    *(const f32x4*)(WT + (size_t)((wn + j_ * 16 + lr) << 9) +      \
                                    kt * 32 + lk));                                \
            _Pragma("unroll") for (int i_ = 0; i_ < 4; ++i_)                       \
                af[i_] = __builtin_bit_cast(bf16x8,                                \
                    *(const f32x4*)(&SRC[(i_ * 16 + lr) * HPAD + kt * 32 + lk]));  \
            _Pragma("unroll") for (int i_ = 0; i_ < 4; ++i_)                       \
                _Pragma("unroll") for (int j_ = 0; j_ < 4; ++j_)                   \
                    acc[i_][j_] = __builtin_amdgcn_mfma_f32_16x16x32_bf16(         \
                        af[i_], bw[j_], acc[i_][j_], 0, 0, 0);                     \
        }                                                                          \
    } while (0)

#define EPI_TANH(BIAS, DST)                                                        \
    do {                                                                           \
        _Pragma("unroll") for (int j_ = 0; j_ < 4; ++j_) {                         \
            const float bv = BIAS[wn + j_ * 16 + lr];                              \
            _Pragma("unroll") for (int i_ = 0; i_ < 4; ++i_) {                     \
                const int rb = i_ * 16 + lq * 4;                                   \
                _Pragma("unroll") for (int r_ = 0; r_ < 4; ++r_)                   \
                    DST[(rb + r_) * HPAD + wn + j_ * 16 + lr] =                    \
                        f2b(fast_tanh(acc[i_][j_][r_] + bv));                      \
            }                                                                      \
        }                                                                          \
    } while (0)

#define EPI_K(KD, GP)                                                              \
    do {                                                                           \
        _Pragma("unroll") for (int j_ = 0; j_ < 4; ++j_) {                         \
            const float bv = bb3[wn + j_ * 16 + lr];                               \
            _Pragma("unroll") for (int i_ = 0; i_ < 4; ++i_) {                     \
                u16x4 kv_;                                                         \
                _Pragma("unroll") for (int r_ = 0; r_ < 4; ++r_)                   \
                    kv_[r_] = f2b(acc[i_][j_][r_] + bv);                           \
                KD[i_][j_] = kv_;                                                  \
                if ((GP) != nullptr)                                               \
                    *(u16x4*)((u16*)(GP) + kbase + (size_t)(i_ * 4 + j_) * 2048) = \
                        kv_;                                                       \
            }                                                                      \
        }                                                                          \
    } while (0)

#define MLP3(KD, GP)                                                               \
    do {                                                                           \
        LAYER(As, W1t);                                                            \
        EPI_TANH(bb1, Hs);                                                         \
        __syncthreads();                                                           \
        LAYER(Hs, W2t);                                                            \
        EPI_TANH(bb2, As);                                                         \
        __syncthreads();                                                           \
        LAYER(As, W3t);                                                            \
        __syncthreads();                                                           \
        EPI_K(KD, GP);                                                             \
    } while (0)

#pragma clang loop unroll(disable)
    for (int st = 0; st < 8; ++st) {
        // e0: s1 = S -> k1 (kA), store G1
        STG_BEGIN STG_END
        __syncthreads();
        MLP3(kA, G1);

        // e1: s2 = S + A21 k1(kA) -> k2 (kB), store G2
        STG_BEGIN ADDT(A21, kA) STG_END
        __syncthreads();
        MLP3(kB, G2);

        // e2: s3 = S + A31 k1(kA) + A32 k2(kB) -> k3 (kA), store G3
        STG_BEGIN ADDT(A31, kA) ADDT(A32, kB) STG_END
        __syncthreads();
        MLP3(kA, G3);

        // e3: s4 = S + A41 k1(G1) + A42 k2(kB) + A43 k3(kA) -> k4 (kB), store G4
        {
            u16x4 g1[4][4];
            k_load(G1, kbase, g1);
            STG_BEGIN ADDT(A41, g1) ADDT(A42, kB) ADDT(A43, kA) STG_END
        }
        __syncthreads();
        MLP3(kB, G4);

        // e4: s5 = S + A51 k1(G1) + A52 k2(G2) + A53 k3(kA) + A54 k4(kB) -> k5 (kA)
        {
            u16x4 g1[4][4], g2[4][4];
            k_load(G1, kbase, g1);
            k_load(G2, kbase, g2);
            STG_BEGIN ADDT(A51, g1) ADDT(A52, g2) ADDT(A53, kA) ADDT(A54, kB) STG_END
        }
        __syncthreads();
        MLP3(kA, (u16*)nullptr);

        // e5: s6 = S + A61 k1 + A62 k2 + A63 k3 + A64 k4(kB) + A65 k5(kA) -> k6 (kB)
        {
            u16x4 g1[4][4], g2[4][4], g3[4][4];
            k_load(G1, kbase, g1);
            k_load(G2, kbase, g2);
            k_load(G3, kbase, g3);
            STG_BEGIN ADDT(A61, g1) ADDT(A62, g2) ADDT(A63, g3) ADDT(A64, kB)
                ADDT(A65, kA) STG_END
        }
        __syncthreads();
        MLP3(kB, (u16*)nullptr);

        // final: S += B1 k1(G1) + B3 k3(G3) + B4 k4(G4) + B5 k5(kA) + B6 k6(kB)
        {
            u16x4 g1[4][4], g3[4][4], g4[4][4];
            k_load(G1, kbase, g1);
            k_load(G3, kbase, g3);
            k_load(G4, kbase, g4);
            const bool last = (st == 7);
#pragma unroll
            for (int i = 0; i < 4; ++i)
#pragma unroll
                for (int j = 0; j < 4; ++j) {
                    u16x4 t1 = g1[i][j], t3 = g3[i][j], t4 = g4[i][j];
                    u16x4 t5 = kA[i][j], t6 = kB[i][j];
#pragma unroll
                    for (int r = 0; r < 4; ++r)
                        S[i][j][r] += B1c * b2f(t1[r]) + B3c * b2f(t3[r]) +
                                      B4c * b2f(t4[r]) + B5c * b2f(t5[r]) +
                                      B6c * b2f(t6[r]);
                    if (last) {
                        const int col = wn + j * 16 + lr;
                        const int rw = i * 16 + lq * 4;
#pragma unroll
                        for (int r = 0; r < 4; ++r)
                            OUT[(row0 + rw + r) * 512 + col] = S[i][j][r];
                    }
                }
        }
    }
#undef MLP3
#undef EPI_K
#undef EPI_TANH
#undef LAYER
#undef STG_END
#undef ADDT
#undef STG_BEGIN
#undef STAGE_STORE
}

// out_bf16[c*R + r] = in_f32[r*Ncols + c]   (weight transpose + cast, tiny)
__global__ void transpose_k(const float* __restrict__ in, u16* __restrict__ out,
                            int R, int Ncols) {
    int idx = blockIdx.x * 256 + threadIdx.x;
    int r = idx / Ncols, c = idx % Ncols;
    out[(size_t)c * R + r] = f2b(in[idx]);
}

extern "C" void kernel_launch(void* const* d_in, const int* in_sizes, int n_in,
                              void* d_out, int out_size, void* d_ws, size_t ws_size,
                              hipStream_t stream) {
    // ---- order-robust input mapping via in_sizes ----
    const float *y = nullptr, *u_t = nullptr, *Wp = nullptr, *bp = nullptr;
    const float *W1 = nullptr, *b1 = nullptr, *W2 = nullptr, *b2 = nullptr;
    const float *W3 = nullptr, *b3 = nullptr;
    {
        const float* w262[3] = {nullptr, nullptr, nullptr};
        const float* s512[4] = {nullptr, nullptr, nullptr, nullptr};
        int i512[4] = {0, 0, 0, 0};
        int n262 = 0, n512 = 0;
        for (int i = 0; i < n_in; ++i) {
            const float* p = (const float*)d_in[i];
            int sz = in_sizes[i];
            if (sz == MDIM * NDIM) y = p;
            else if (sz == MDIM * 256) u_t = p;
            else if (sz == 256 * 512) Wp = p;
            else if (sz == 512 * 512) { if (n262 < 3) w262[n262++] = p; }
            else if (sz == 512) { if (n512 < 4) { i512[n512] = i; s512[n512++] = p; } }
        }
        W1 = w262[0]; W2 = w262[1]; W3 = w262[2];
        bool contig = (n512 == 4) && (i512[3] == i512[0] + 3);
        if (contig) { b1 = s512[0]; b2 = s512[1]; b3 = s512[2]; bp = s512[3]; }
        else        { bp = s512[0]; b1 = s512[1]; b2 = s512[2]; b3 = s512[3]; }
        if (!y || !u_t || !Wp || !W1 || n512 < 4) {  // fallback: dict order
            y  = (const float*)d_in[0]; u_t = (const float*)d_in[1];
            Wp = (const float*)d_in[2]; bp  = (const float*)d_in[3];
            W1 = (const float*)d_in[4]; b1  = (const float*)d_in[5];
            W2 = (const float*)d_in[6]; b2  = (const float*)d_in[7];
            W3 = (const float*)d_in[8]; b3  = (const float*)d_in[9];
        }
    }

    u16* ws  = (u16*)d_ws;
    u16* Wpt = ws;                    // 512x256 bf16  (N x K, K contiguous)
    u16* W1t = Wpt + 512 * 256;       // 512x512 bf16
    u16* W2t = W1t + 512 * 512;
    u16* W3t = W2t + 512 * 512;
    const size_t wfix = 512 * 256 + 3 * 512 * 512;   // 917504 u16 = 1.84 MB

    // per-row workspace: S32 fp32 (1024 u16) + K1..K4 fragment-packed bf16 (4*512 u16)
    long wsElems = (long)(ws_size / 2);
    long chunk = (wsElems - (long)wfix) / (6L * NDIM);
    chunk = (chunk / 128) * 128;
    if (chunk > MDIM) chunk = MDIM;
    if (chunk < 128) chunk = 128;

    transpose_k<<<512, 256, 0, stream>>>(Wp, Wpt, 256, 512);
    transpose_k<<<1024, 256, 0, stream>>>(W1, W1t, 512, 512);
    transpose_k<<<1024, 256, 0, stream>>>(W2, W2t, 512, 512);
    transpose_k<<<1024, 256, 0, stream>>>(W3, W3t, 512, 512);

    float* OUT = (float*)d_out;   // fp32 output, per reference dtype

    for (long row0 = 0; row0 < MDIM; row0 += chunk) {
        const long rows = (MDIM - row0 < chunk) ? (MDIM - row0) : chunk;
        const size_t CB = (size_t)rows * NDIM;

        u16* base = ws + wfix;
        float* S32 = (float*)base;          // 2*CB u16
        u16* G1 = base + 2 * CB;
        u16* G2 = base + 3 * CB;
        u16* G3 = base + 4 * CB;
        u16* G4 = base + 5 * CB;

        // S32 = u_t @ Wp + bp + y  (fp32 only)
        dim3 gg(4, (unsigned)(rows / 128));
        gemm_bt<256, 3, true><<<gg, 256, 0, stream>>>(
            (const void*)(u_t + (size_t)row0 * 256), Wpt, bp,
            y + (size_t)row0 * NDIM, nullptr, S32);

        // all 8 steps x 6 evals fused; S and the two newest k's in registers
        const int nb = (int)(rows / 64);
        ode_mega<<<nb, 512, 0, stream>>>(
            S32, W1t, b1, W2t, b2, W3t, b3,
            G1, G2, G3, G4,
            OUT + (size_t)row0 * NDIM);
    }
}